// Round 2
// baseline (556.913 us; speedup 1.0000x reference)
//
#include <hip/hip_runtime.h>
#include <math.h>

#define BB 16
#define MM 2048
#define SS 6
#define EE 128
#define LCC 512
#define VV 32000

typedef __attribute__((ext_vector_type(8))) __bf16 bf16x8;
typedef __attribute__((ext_vector_type(4))) float f32x4;

#define XS_STRIDE 264   // 256+8 bf16 pad
#define HS_STRIDE 136   // 128+8 bf16 pad

static __device__ inline unsigned short bfbits(float x) {
    __bf16 h = (__bf16)x;
    return __builtin_bit_cast(unsigned short, h);
}

// ---------------------------------------------------------------------------
// prep_small: W1/W2 fp32 -> bf16 transposed [n][k]; uqA = uqB = 0; bar = 0.
// ---------------------------------------------------------------------------
#define N_W1  (256 * 128)              // 32,768
#define N_W2  (128 * 128)              // 16,384
#define N_UQ  (BB * EE)                // 2,048
#define N_BAR 256                      // barrier counters (4 used, line-padded)
#define N_PREP (N_W1 + N_W2 + 2 * N_UQ + N_BAR)

__global__ __launch_bounds__(256)
void prep_small(const float* __restrict__ W1, const float* __restrict__ W2,
                __bf16* __restrict__ w1t, __bf16* __restrict__ w2t,
                float* __restrict__ uqA, float* __restrict__ uqB,
                int* __restrict__ bar)
{
    int i = blockIdx.x * 256 + threadIdx.x;
    if (i < N_W1) { const int n = i >> 8, k = i & 255; w1t[i] = (__bf16)W1[k * EE + n]; return; }
    i -= N_W1;
    if (i < N_W2) { const int n = i >> 7, k = i & 127; w2t[i] = (__bf16)W2[k * EE + n]; return; }
    i -= N_W2;
    if (i < N_UQ) { uqA[i] = 0.f; return; }
    i -= N_UQ;
    if (i < N_UQ) { uqB[i] = 0.f; return; }
    i -= N_UQ;
    if (i < N_BAR) { bar[i] = 0; }
}

// ---------------------------------------------------------------------------
// Fused embed gather-sum (fp32 C, direct) + add_lm + MFMA MLP, 3 hops.
// hop 0: logits0 in-register, m0 never stored. hops 1,2: Y -> mout bf16.
// LDS: Hs/plog ALIAS Xs (Xs dead after GEMM1 K-loop; barrier-separated).
// ---------------------------------------------------------------------------
__global__ __launch_bounds__(256)
void embed_mlp_mfma(const int* __restrict__ story,
                    const int* __restrict__ kb_len,
                    const int* __restrict__ conv_len,
                    const float* __restrict__ dh,
                    const float* __restrict__ tf,
                    const float* __restrict__ C,
                    const __bf16* __restrict__ w1t, const float* __restrict__ b1,
                    const __bf16* __restrict__ w2t, const float* __restrict__ b2,
                    const float* __restrict__ gp, const float* __restrict__ query,
                    __bf16* __restrict__ mout, float* __restrict__ lbuf0)
{
    __shared__ __bf16 Xs[32 * XS_STRIDE];   // 16,896 B; Hs (8,704 B) aliases
    __shared__ int    sidx[32 * SS];
    __bf16* Hs   = Xs;                      // valid: Xs dead before H written
    float*  plog = (float*)Xs;              // valid: Hs dead before plog written

    const int bid  = blockIdx.x;
    const int hop  = bid >> 10;
    const int row0 = (bid & 1023) * 32;
    const int b    = row0 >> 11;
    const int tid  = threadIdx.x;

    const float* Ck = C + (size_t)hop * VV * EE;

    for (int i = tid; i < 32 * SS; i += 256) sidx[i] = story[(size_t)row0 * SS + i];

    const int kb   = kb_len[b];
    const int cl   = conv_len[b];
    const int rgrp = tid >> 5;              // 0..7
    const int e4   = (tid & 31) * 4;        // 4-float col group
    const float4 tf4 = *(const float4*)&tf[b * EE + e4];
    ushort4 tfp;
    tfp.x = bfbits(tf4.x); tfp.y = bfbits(tf4.y); tfp.z = bfbits(tf4.z); tfp.w = bfbits(tf4.w);
    __syncthreads();

    // ---- gather X: fp32 float4 reads, packed bf16x4 LDS stores ----
    for (int chunk = 0; chunk < 4; ++chunk) {
        const int r  = chunk * 8 + rgrp;
        const int* si = &sidx[r * SS];
        float4 v[SS];
        #pragma unroll
        for (int s = 0; s < SS; ++s)
            v[s] = *(const float4*)&Ck[(size_t)si[s] * EE + e4];
        const int j = ((row0 + r) & (MM - 1)) - kb;
        float4 acc = {0.f, 0.f, 0.f, 0.f};
        if (j >= 0 && j < cl)
            acc = *(const float4*)&dh[((size_t)b * LCC + j) * EE + e4];
        #pragma unroll
        for (int s = 0; s < SS; ++s) {
            acc.x += v[s].x; acc.y += v[s].y; acc.z += v[s].z; acc.w += v[s].w;
        }
        ushort4 pk;
        pk.x = bfbits(acc.x); pk.y = bfbits(acc.y); pk.z = bfbits(acc.z); pk.w = bfbits(acc.w);
        *(ushort4*)&Xs[r * XS_STRIDE + e4]      = pk;
        *(ushort4*)&Xs[r * XS_STRIDE + EE + e4] = tfp;
    }
    __syncthreads();

    const int w       = tid >> 6;
    const int lane    = tid & 63;
    const int lr      = lane & 15;
    const int lk      = lane >> 4;
    const int colbase = w * 32;

    // ---- GEMM1: H = lrelu(X @ W1 + b1) ----
    f32x4 acc1[2][2];
    #pragma unroll
    for (int i = 0; i < 2; ++i)
        #pragma unroll
        for (int j = 0; j < 2; ++j) acc1[i][j] = (f32x4){0.f, 0.f, 0.f, 0.f};

    for (int ks = 0; ks < 8; ++ks) {
        bf16x8 a[2], bw[2];
        #pragma unroll
        for (int mt = 0; mt < 2; ++mt)
            a[mt] = *(const bf16x8*)&Xs[(mt * 16 + lr) * XS_STRIDE + ks * 32 + lk * 8];
        #pragma unroll
        for (int nt = 0; nt < 2; ++nt)
            bw[nt] = *(const bf16x8*)&w1t[(size_t)(colbase + nt * 16 + lr) * 256 + ks * 32 + lk * 8];
        #pragma unroll
        for (int mt = 0; mt < 2; ++mt)
            #pragma unroll
            for (int nt = 0; nt < 2; ++nt)
                acc1[mt][nt] = __builtin_amdgcn_mfma_f32_16x16x32_bf16(a[mt], bw[nt], acc1[mt][nt], 0, 0, 0);
    }
    __syncthreads();   // all Xs reads complete before Hs (alias) is written
    {
        const float b1v[2] = { b1[colbase + lr], b1[colbase + 16 + lr] };
        #pragma unroll
        for (int mt = 0; mt < 2; ++mt)
            #pragma unroll
            for (int nt = 0; nt < 2; ++nt)
                #pragma unroll
                for (int reg = 0; reg < 4; ++reg) {
                    float h = acc1[mt][nt][reg] + b1v[nt];
                    h = (h > 0.f) ? h : 0.1f * h;
                    Hs[(mt * 16 + lk * 4 + reg) * HS_STRIDE + colbase + nt * 16 + lr] = (__bf16)h;
                }
    }
    __syncthreads();

    // ---- GEMM2: Y = H @ W2 + b2 ----
    f32x4 acc2[2][2];
    #pragma unroll
    for (int i = 0; i < 2; ++i)
        #pragma unroll
        for (int j = 0; j < 2; ++j) acc2[i][j] = (f32x4){0.f, 0.f, 0.f, 0.f};

    for (int ks = 0; ks < 4; ++ks) {
        bf16x8 a[2], bw[2];
        #pragma unroll
        for (int mt = 0; mt < 2; ++mt)
            a[mt] = *(const bf16x8*)&Hs[(mt * 16 + lr) * HS_STRIDE + ks * 32 + lk * 8];
        #pragma unroll
        for (int nt = 0; nt < 2; ++nt)
            bw[nt] = *(const bf16x8*)&w2t[(size_t)(colbase + nt * 16 + lr) * 128 + ks * 32 + lk * 8];
        #pragma unroll
        for (int mt = 0; mt < 2; ++mt)
            #pragma unroll
            for (int nt = 0; nt < 2; ++nt)
                acc2[mt][nt] = __builtin_amdgcn_mfma_f32_16x16x32_bf16(a[mt], bw[nt], acc2[mt][nt], 0, 0, 0);
    }

    const float b2v[2] = { b2[colbase + lr], b2[colbase + 16 + lr] };

    if (hop == 0) {
        const float qv0 = query[b * EE + colbase + lr];
        const float qv1 = query[b * EE + colbase + 16 + lr];
        __syncthreads();    // Hs reads done; reuse as plog
        #pragma unroll
        for (int mt = 0; mt < 2; ++mt)
            #pragma unroll
            for (int reg = 0; reg < 4; ++reg) {
                float p = (acc2[mt][0][reg] + b2v[0]) * qv0
                        + (acc2[mt][1][reg] + b2v[1]) * qv1;
                p += __shfl_xor(p, 1, 64);
                p += __shfl_xor(p, 2, 64);
                p += __shfl_xor(p, 4, 64);
                p += __shfl_xor(p, 8, 64);
                if (lr == 0) plog[(mt * 16 + lk * 4 + reg) * 4 + w] = p;
            }
        __syncthreads();
        if (tid < 32) {
            const float l = plog[tid * 4] + plog[tid * 4 + 1] + plog[tid * 4 + 2] + plog[tid * 4 + 3];
            lbuf0[row0 + tid] = l * gp[row0 + tid];
        }
    } else {
        __bf16* out = mout + (size_t)(hop - 1) * 32768 * EE;
        #pragma unroll
        for (int mt = 0; mt < 2; ++mt)
            #pragma unroll
            for (int nt = 0; nt < 2; ++nt)
                #pragma unroll
                for (int reg = 0; reg < 4; ++reg) {
                    const int rg_ = row0 + mt * 16 + lk * 4 + reg;
                    out[(size_t)rg_ * EE + colbase + nt * 16 + lr] =
                        (__bf16)(acc2[mt][nt][reg] + b2v[nt]);
                }
    }
}

// ---------------------------------------------------------------------------
// Custom device-wide barrier.  512 blocks (2/CU, 3 KB LDS, ~40 VGPR) are
// trivially co-resident -> spin cannot deadlock.  Counters zeroed by
// prep_small each invocation (same stream, serialized before fused_tail).
// cg::grid.sync() measured 85 µs/sync on gfx950 — this replaces it.
// ---------------------------------------------------------------------------
static __device__ inline void grid_barrier(int* cnt, int expected, int tid)
{
    __threadfence();            // flush this thread's global writes (agent scope)
    __syncthreads();            // all threads in block fenced
    if (tid == 0) {
        __hip_atomic_fetch_add(cnt, 1, __ATOMIC_RELEASE, __HIP_MEMORY_SCOPE_AGENT);
        while (__hip_atomic_load(cnt, __ATOMIC_ACQUIRE, __HIP_MEMORY_SCOPE_AGENT) < expected)
            __builtin_amdgcn_s_sleep(2);
    }
    __syncthreads();
    __threadfence();            // invalidate stale cached lines before reads
}

// ---------------------------------------------------------------------------
// fused_tail: ONE kernel replacing update1/logits1/update2/logits2/softmax.
// ---------------------------------------------------------------------------
static __device__ inline void update_phase(
    const __bf16* __restrict__ mk, const float* __restrict__ gp,
    const float* __restrict__ lbuf, float* __restrict__ uq,
    int b, int rloc0, int tid, int lane, int w,
    float* redm, float* reds, float* wls, float (*part)[128])
{
    const float* lb = lbuf + (size_t)b * MM;
    float v[8];
    float mx = -1e30f;
    #pragma unroll
    for (int i = 0; i < 8; ++i) { v[i] = lb[i * 256 + tid]; mx = fmaxf(mx, v[i]); }
    #pragma unroll
    for (int off = 32; off > 0; off >>= 1) mx = fmaxf(mx, __shfl_xor(mx, off, 64));
    if (lane == 0) redm[w] = mx;
    __syncthreads();
    mx = fmaxf(fmaxf(redm[0], redm[1]), fmaxf(redm[2], redm[3]));
    float sum = 0.f;
    #pragma unroll
    for (int i = 0; i < 8; ++i) sum += __expf(v[i] - mx);
    #pragma unroll
    for (int off = 32; off > 0; off >>= 1) sum += __shfl_xor(sum, off, 64);
    if (lane == 0) reds[w] = sum;
    __syncthreads();
    const float inv = 1.f / (reds[0] + reds[1] + reds[2] + reds[3]);

    if (tid < 64)
        wls[tid] = gp[(size_t)b * MM + rloc0 + tid] * __expf(lb[rloc0 + tid] - mx) * inv;
    __syncthreads();

    const int rgrp = tid >> 4;
    const int e8   = (tid & 15) * 8;
    float acc[8];
    #pragma unroll
    for (int q = 0; q < 8; ++q) acc[q] = 0.f;
    #pragma unroll
    for (int p = 0; p < 4; ++p) {
        const int rl  = p * 16 + rgrp;
        const float wg = wls[rl];
        const bf16x8 vv = *(const bf16x8*)&mk[((size_t)b * MM + rloc0 + rl) * EE + e8];
        #pragma unroll
        for (int q = 0; q < 8; ++q) acc[q] += wg * (float)vv[q];
    }
    #pragma unroll
    for (int q = 0; q < 8; ++q) {
        acc[q] += __shfl_xor(acc[q], 16, 64);
        acc[q] += __shfl_xor(acc[q], 32, 64);
    }
    if (lane < 16) {
        #pragma unroll
        for (int q = 0; q < 8; ++q) part[w][e8 + q] = acc[q];
    }
    __syncthreads();
    if (tid < 128) {
        const float s = part[0][tid] + part[1][tid] + part[2][tid] + part[3][tid];
        atomicAdd(&uq[b * EE + tid], s);
    }
}

static __device__ inline void logits_phase(
    const __bf16* __restrict__ mk, const float* __restrict__ gp,
    const float* __restrict__ query, const float* __restrict__ uqa,
    const float* __restrict__ uqb, float* __restrict__ out,
    int bid, int b, int tid, int lane, int w, float* uqs)
{
    const int row0 = bid * 64;
    if (tid < 128)
        uqs[tid] = query[b * EE + tid] + uqa[b * EE + tid]
                 + (uqb ? uqb[b * EE + tid] : 0.f);
    __syncthreads();
    const int g = lane >> 4, l16 = lane & 15;
    float u[8];
    #pragma unroll
    for (int j = 0; j < 8; ++j) u[j] = uqs[l16 * 8 + j];
    #pragma unroll
    for (int it = 0; it < 4; ++it) {
        const int row = row0 + it * 16 + w * 4 + g;
        const bf16x8 v = *(const bf16x8*)&mk[(size_t)row * EE + l16 * 8];
        float p = 0.f;
        #pragma unroll
        for (int j = 0; j < 8; ++j) p += (float)v[j] * u[j];
        p += __shfl_xor(p, 1, 64);
        p += __shfl_xor(p, 2, 64);
        p += __shfl_xor(p, 4, 64);
        p += __shfl_xor(p, 8, 64);
        if (l16 == 0) out[row] = p * gp[row];
    }
    __syncthreads();
}

__global__ __launch_bounds__(256)
void fused_tail(const __bf16* __restrict__ mall, const float* __restrict__ gp,
                const float* __restrict__ query, float* __restrict__ lbuf,
                float* __restrict__ uqA, float* __restrict__ uqB,
                float* __restrict__ out_logits, float* __restrict__ out_soft,
                int* __restrict__ bar)
{
    __shared__ float redm[4], reds[4];
    __shared__ float wls[64];
    __shared__ float part[4][128];
    __shared__ float uqs[128];

    const int bid   = blockIdx.x;          // 0..511
    const int b     = bid >> 5;
    const int rloc0 = (bid & 31) * 64;
    const int tid   = threadIdx.x;
    const int lane  = tid & 63;
    const int w     = tid >> 6;
    const int nblk  = gridDim.x;

    const __bf16* m1 = mall;
    const __bf16* m2 = mall + (size_t)32768 * EE;

    // hop1: uqA += m1^T (gp * softmax(lbuf0))
    update_phase(m1, gp, lbuf, uqA, b, rloc0, tid, lane, w, redm, reds, wls, part);
    grid_barrier(bar + 0 * 32, nblk, tid);

    // logits1 = gp * (m1 (query+uqA)) -> lbuf
    logits_phase(m1, gp, query, uqA, nullptr, lbuf, bid, b, tid, lane, w, uqs);
    grid_barrier(bar + 1 * 32, nblk, tid);

    // hop2: uqB += m2^T (gp * softmax(lbuf))
    update_phase(m2, gp, lbuf, uqB, b, rloc0, tid, lane, w, redm, reds, wls, part);
    grid_barrier(bar + 2 * 32, nblk, tid);

    // logits2 = gp * (m2 (query+uqA+uqB)) -> out_logits
    logits_phase(m2, gp, query, uqA, uqB, out_logits, bid, b, tid, lane, w, uqs);
    grid_barrier(bar + 3 * 32, nblk, tid);

    // final softmax: every block reduces its b's full row, writes its 64-row seg
    {
        const float* lb = out_logits + (size_t)b * MM;
        float v[8];
        float mx = -1e30f;
        #pragma unroll
        for (int i = 0; i < 8; ++i) { v[i] = lb[i * 256 + tid]; mx = fmaxf(mx, v[i]); }
        #pragma unroll
        for (int off = 32; off > 0; off >>= 1) mx = fmaxf(mx, __shfl_xor(mx, off, 64));
        if (lane == 0) redm[w] = mx;
        __syncthreads();
        mx = fmaxf(fmaxf(redm[0], redm[1]), fmaxf(redm[2], redm[3]));
        float sum = 0.f;
        #pragma unroll
        for (int i = 0; i < 8; ++i) sum += __expf(v[i] - mx);
        #pragma unroll
        for (int off = 32; off > 0; off >>= 1) sum += __shfl_xor(sum, off, 64);
        if (lane == 0) reds[w] = sum;
        __syncthreads();
        const float inv = 1.f / (reds[0] + reds[1] + reds[2] + reds[3]);
        if (tid < 64)
            out_soft[(size_t)b * MM + rloc0 + tid] =
                __expf(lb[rloc0 + tid] - mx) * inv;
    }
}

// ---------------------------------------------------------------------------
extern "C" void kernel_launch(void* const* d_in, const int* in_sizes, int n_in,
                              void* d_out, int out_size, void* d_ws, size_t ws_size,
                              hipStream_t stream) {
    const int*   story    = (const int*)d_in[0];
    const int*   kb_len   = (const int*)d_in[1];
    const int*   conv_len = (const int*)d_in[2];
    // d_in[3] = hidden (dead w.r.t. outputs)
    const float* dh       = (const float*)d_in[4];
    const float* tf       = (const float*)d_in[5];
    const float* query    = (const float*)d_in[6];
    const float* gp       = (const float*)d_in[7];
    const float* C        = (const float*)d_in[8];
    const float* wA1      = (const float*)d_in[9];
    const float* bA1      = (const float*)d_in[10];
    const float* wA2      = (const float*)d_in[11];
    const float* bA2      = (const float*)d_in[12];
    // wC1/bC1/wC2/bC2, wf/bf: dead w.r.t. outputs

    char* ws = (char*)d_ws;
    const size_t M_ELEMS = (size_t)32768 * EE;
    size_t off = 0;
    __bf16* m   = (__bf16*)(ws + off); off += 2 * M_ELEMS * sizeof(__bf16);    // m1, m2
    __bf16* w1t = (__bf16*)(ws + off); off += 256 * 128 * sizeof(__bf16);
    __bf16* w2t = (__bf16*)(ws + off); off += 128 * 128 * sizeof(__bf16);
    float* lbuf = (float*)(ws + off);  off += (size_t)BB * MM * sizeof(float);
    float* uqA  = (float*)(ws + off);  off += (size_t)BB * EE * sizeof(float);
    float* uqB  = (float*)(ws + off);  off += (size_t)BB * EE * sizeof(float);
    int*   bar  = (int*)(ws + off);    off += N_BAR * sizeof(int);

    float* out_soft   = (float*)d_out;
    float* out_logits = out_soft + (size_t)BB * MM;

    prep_small<<<(N_PREP + 255) / 256, 256, 0, stream>>>(wA1, wA2, w1t, w2t, uqA, uqB, bar);
    embed_mlp_mfma<<<3072, 256, 0, stream>>>(story, kb_len, conv_len, dh, tf, C,
                                             w1t, bA1, w2t, bA2, gp, query, m, lbuf);
    fused_tail<<<512, 256, 0, stream>>>(m, gp, query, lbuf, uqA, uqB,
                                        out_logits, out_soft, bar);
}

// Round 4
// 212.461 us; speedup vs baseline: 2.6213x; 2.6213x over previous
//
#include <hip/hip_runtime.h>
#include <math.h>

#define BB 16
#define MM 2048
#define SS 6
#define EE 128
#define LCC 512
#define VV 32000

typedef __attribute__((ext_vector_type(8))) __bf16 bf16x8;
typedef __attribute__((ext_vector_type(4))) float f32x4;

#define XS_STRIDE 264   // 256+8 bf16 pad
#define HS_STRIDE 136   // 128+8 bf16 pad

static __device__ inline unsigned short bfbits(float x) {
    __bf16 h = (__bf16)x;
    return __builtin_bit_cast(unsigned short, h);
}

// ---------------------------------------------------------------------------
// prep_small: W1/W2 fp32 -> bf16 transposed [n][k].
// ---------------------------------------------------------------------------
#define N_W1  (256 * 128)              // 32,768
#define N_W2  (128 * 128)              // 16,384
#define N_PREP (N_W1 + N_W2)           // 49,152 = 192*256

__global__ __launch_bounds__(256)
void prep_small(const float* __restrict__ W1, const float* __restrict__ W2,
                __bf16* __restrict__ w1t, __bf16* __restrict__ w2t)
{
    int i = blockIdx.x * 256 + threadIdx.x;
    if (i < N_W1) { const int n = i >> 8, k = i & 255; w1t[i] = (__bf16)W1[k * EE + n]; return; }
    i -= N_W1;
    if (i < N_W2) { const int n = i >> 7, k = i & 127; w2t[i] = (__bf16)W2[k * EE + n]; }
}

// ---------------------------------------------------------------------------
// Fused embed gather-sum (fp32 C, direct) + add_lm + MFMA MLP, 3 hops.
// hop 0: logits0 in-register, m0 never stored. hops 1,2: Y -> mout bf16.
// LDS: Hs/plog ALIAS Xs (Xs dead after GEMM1 K-loop; barrier-separated).
// ---------------------------------------------------------------------------
__global__ __launch_bounds__(256)
void embed_mlp_mfma(const int* __restrict__ story,
                    const int* __restrict__ kb_len,
                    const int* __restrict__ conv_len,
                    const float* __restrict__ dh,
                    const float* __restrict__ tf,
                    const float* __restrict__ C,
                    const __bf16* __restrict__ w1t, const float* __restrict__ b1,
                    const __bf16* __restrict__ w2t, const float* __restrict__ b2,
                    const float* __restrict__ gp, const float* __restrict__ query,
                    __bf16* __restrict__ mout, float* __restrict__ lbuf0)
{
    __shared__ __bf16 Xs[32 * XS_STRIDE];   // 16,896 B; Hs (8,704 B) aliases
    __shared__ int    sidx[32 * SS];
    __bf16* Hs   = Xs;                      // valid: Xs dead before H written
    float*  plog = (float*)Xs;              // valid: Hs dead before plog written

    const int bid  = blockIdx.x;
    const int hop  = bid >> 10;
    const int row0 = (bid & 1023) * 32;
    const int b    = row0 >> 11;
    const int tid  = threadIdx.x;

    const float* Ck = C + (size_t)hop * VV * EE;

    for (int i = tid; i < 32 * SS; i += 256) sidx[i] = story[(size_t)row0 * SS + i];

    const int kb   = kb_len[b];
    const int cl   = conv_len[b];
    const int rgrp = tid >> 5;              // 0..7
    const int e4   = (tid & 31) * 4;        // 4-float col group
    const float4 tf4 = *(const float4*)&tf[b * EE + e4];
    ushort4 tfp;
    tfp.x = bfbits(tf4.x); tfp.y = bfbits(tf4.y); tfp.z = bfbits(tf4.z); tfp.w = bfbits(tf4.w);
    __syncthreads();

    // ---- gather X: fp32 float4 reads, packed bf16x4 LDS stores ----
    for (int chunk = 0; chunk < 4; ++chunk) {
        const int r  = chunk * 8 + rgrp;
        const int* si = &sidx[r * SS];
        float4 v[SS];
        #pragma unroll
        for (int s = 0; s < SS; ++s)
            v[s] = *(const float4*)&Ck[(size_t)si[s] * EE + e4];
        const int j = ((row0 + r) & (MM - 1)) - kb;
        float4 acc = {0.f, 0.f, 0.f, 0.f};
        if (j >= 0 && j < cl)
            acc = *(const float4*)&dh[((size_t)b * LCC + j) * EE + e4];
        #pragma unroll
        for (int s = 0; s < SS; ++s) {
            acc.x += v[s].x; acc.y += v[s].y; acc.z += v[s].z; acc.w += v[s].w;
        }
        ushort4 pk;
        pk.x = bfbits(acc.x); pk.y = bfbits(acc.y); pk.z = bfbits(acc.z); pk.w = bfbits(acc.w);
        *(ushort4*)&Xs[r * XS_STRIDE + e4]      = pk;
        *(ushort4*)&Xs[r * XS_STRIDE + EE + e4] = tfp;
    }
    __syncthreads();

    const int w       = tid >> 6;
    const int lane    = tid & 63;
    const int lr      = lane & 15;
    const int lk      = lane >> 4;
    const int colbase = w * 32;

    // ---- GEMM1: H = lrelu(X @ W1 + b1) ----
    f32x4 acc1[2][2];
    #pragma unroll
    for (int i = 0; i < 2; ++i)
        #pragma unroll
        for (int j = 0; j < 2; ++j) acc1[i][j] = (f32x4){0.f, 0.f, 0.f, 0.f};

    for (int ks = 0; ks < 8; ++ks) {
        bf16x8 a[2], bw[2];
        #pragma unroll
        for (int mt = 0; mt < 2; ++mt)
            a[mt] = *(const bf16x8*)&Xs[(mt * 16 + lr) * XS_STRIDE + ks * 32 + lk * 8];
        #pragma unroll
        for (int nt = 0; nt < 2; ++nt)
            bw[nt] = *(const bf16x8*)&w1t[(size_t)(colbase + nt * 16 + lr) * 256 + ks * 32 + lk * 8];
        #pragma unroll
        for (int mt = 0; mt < 2; ++mt)
            #pragma unroll
            for (int nt = 0; nt < 2; ++nt)
                acc1[mt][nt] = __builtin_amdgcn_mfma_f32_16x16x32_bf16(a[mt], bw[nt], acc1[mt][nt], 0, 0, 0);
    }
    __syncthreads();   // all Xs reads complete before Hs (alias) is written
    {
        const float b1v[2] = { b1[colbase + lr], b1[colbase + 16 + lr] };
        #pragma unroll
        for (int mt = 0; mt < 2; ++mt)
            #pragma unroll
            for (int nt = 0; nt < 2; ++nt)
                #pragma unroll
                for (int reg = 0; reg < 4; ++reg) {
                    float h = acc1[mt][nt][reg] + b1v[nt];
                    h = (h > 0.f) ? h : 0.1f * h;
                    Hs[(mt * 16 + lk * 4 + reg) * HS_STRIDE + colbase + nt * 16 + lr] = (__bf16)h;
                }
    }
    __syncthreads();

    // ---- GEMM2: Y = H @ W2 + b2 ----
    f32x4 acc2[2][2];
    #pragma unroll
    for (int i = 0; i < 2; ++i)
        #pragma unroll
        for (int j = 0; j < 2; ++j) acc2[i][j] = (f32x4){0.f, 0.f, 0.f, 0.f};

    for (int ks = 0; ks < 4; ++ks) {
        bf16x8 a[2], bw[2];
        #pragma unroll
        for (int mt = 0; mt < 2; ++mt)
            a[mt] = *(const bf16x8*)&Hs[(mt * 16 + lr) * HS_STRIDE + ks * 32 + lk * 8];
        #pragma unroll
        for (int nt = 0; nt < 2; ++nt)
            bw[nt] = *(const bf16x8*)&w2t[(size_t)(colbase + nt * 16 + lr) * 128 + ks * 32 + lk * 8];
        #pragma unroll
        for (int mt = 0; mt < 2; ++mt)
            #pragma unroll
            for (int nt = 0; nt < 2; ++nt)
                acc2[mt][nt] = __builtin_amdgcn_mfma_f32_16x16x32_bf16(a[mt], bw[nt], acc2[mt][nt], 0, 0, 0);
    }

    const float b2v[2] = { b2[colbase + lr], b2[colbase + 16 + lr] };

    if (hop == 0) {
        const float qv0 = query[b * EE + colbase + lr];
        const float qv1 = query[b * EE + colbase + 16 + lr];
        __syncthreads();    // Hs reads done; reuse as plog
        #pragma unroll
        for (int mt = 0; mt < 2; ++mt)
            #pragma unroll
            for (int reg = 0; reg < 4; ++reg) {
                float p = (acc2[mt][0][reg] + b2v[0]) * qv0
                        + (acc2[mt][1][reg] + b2v[1]) * qv1;
                p += __shfl_xor(p, 1, 64);
                p += __shfl_xor(p, 2, 64);
                p += __shfl_xor(p, 4, 64);
                p += __shfl_xor(p, 8, 64);
                if (lr == 0) plog[(mt * 16 + lk * 4 + reg) * 4 + w] = p;
            }
        __syncthreads();
        if (tid < 32) {
            const float l = plog[tid * 4] + plog[tid * 4 + 1] + plog[tid * 4 + 2] + plog[tid * 4 + 3];
            lbuf0[row0 + tid] = l * gp[row0 + tid];
        }
    } else {
        __bf16* out = mout + (size_t)(hop - 1) * 32768 * EE;
        #pragma unroll
        for (int mt = 0; mt < 2; ++mt)
            #pragma unroll
            for (int nt = 0; nt < 2; ++nt)
                #pragma unroll
                for (int reg = 0; reg < 4; ++reg) {
                    const int rg_ = row0 + mt * 16 + lk * 4 + reg;
                    out[(size_t)rg_ * EE + colbase + nt * 16 + lr] =
                        (__bf16)(acc2[mt][nt][reg] + b2v[nt]);
                }
    }
}

// ---------------------------------------------------------------------------
// tail_kernel: ONE block per batch element (16 blocks x 1024 threads).
// Entire tail (softmax0 -> uqA -> logits1 -> softmax1 -> uqB -> logits2 ->
// final softmax) runs inside one block with only __syncthreads().
// No device-wide sync (measured 85-95 us/barrier on gfx950 — dead end).
// Per-block traffic: m1[b] x2 + m2[b] x2 = 2.1 MB (2nd pass L2-hot, 512KB << 4MB).
// ---------------------------------------------------------------------------
static __device__ inline void softmax_weights(
    const float* __restrict__ src, const float* __restrict__ gls,
    float* __restrict__ wls, float* redm, float* reds,
    int tid, int wv, int lane)
{
    const float v0 = src[tid], v1 = src[tid + 1024];
    float mx = fmaxf(v0, v1);
    #pragma unroll
    for (int off = 32; off > 0; off >>= 1) mx = fmaxf(mx, __shfl_xor(mx, off, 64));
    if (lane == 0) redm[wv] = mx;
    __syncthreads();
    mx = redm[0];
    #pragma unroll
    for (int k = 1; k < 16; ++k) mx = fmaxf(mx, redm[k]);
    const float e0 = __expf(v0 - mx), e1 = __expf(v1 - mx);
    float sum = e0 + e1;
    #pragma unroll
    for (int off = 32; off > 0; off >>= 1) sum += __shfl_xor(sum, off, 64);
    if (lane == 0) reds[wv] = sum;
    __syncthreads();
    float tot = reds[0];
    #pragma unroll
    for (int k = 1; k < 16; ++k) tot += reds[k];
    const float inv = 1.f / tot;
    wls[tid]        = gls[tid]        * e0 * inv;
    wls[tid + 1024] = gls[tid + 1024] * e1 * inv;
    __syncthreads();
}

static __device__ inline void update_u(
    const __bf16* __restrict__ mk, const float* __restrict__ wls,
    float (*part)[128], float* __restrict__ ured,
    int tid, int wv, int lane)
{
    const int rgrp = tid >> 4;          // 0..63
    const int e8   = (tid & 15) * 8;
    float acc[8];
    #pragma unroll
    for (int q = 0; q < 8; ++q) acc[q] = 0.f;
    for (int p = 0; p < 32; ++p) {
        const int r = p * 64 + rgrp;
        const float wg = wls[r];
        const bf16x8 vv = *(const bf16x8*)&mk[(size_t)r * EE + e8];
        #pragma unroll
        for (int q = 0; q < 8; ++q) acc[q] += wg * (float)vv[q];
    }
    #pragma unroll
    for (int q = 0; q < 8; ++q) {
        acc[q] += __shfl_xor(acc[q], 16, 64);
        acc[q] += __shfl_xor(acc[q], 32, 64);
    }
    if (lane < 16) {
        #pragma unroll
        for (int q = 0; q < 8; ++q) part[wv][lane * 8 + q] = acc[q];
    }
    __syncthreads();
    if (tid < 128) {
        float s = 0.f;
        #pragma unroll
        for (int k = 0; k < 16; ++k) s += part[k][tid];
        ured[tid] += s;
    }
    __syncthreads();
}

static __device__ inline void logits_u(
    const __bf16* __restrict__ mk, const float* __restrict__ gls,
    const float* __restrict__ uvec, float* __restrict__ slog,
    int tid, int wv, int lane)
{
    const int g = lane >> 4, l16 = lane & 15;
    float u[8];
    #pragma unroll
    for (int j = 0; j < 8; ++j) u[j] = uvec[l16 * 8 + j];
    for (int it = 0; it < 32; ++it) {
        const int row = it * 64 + wv * 4 + g;
        const bf16x8 v = *(const bf16x8*)&mk[(size_t)row * EE + l16 * 8];
        float p = 0.f;
        #pragma unroll
        for (int j = 0; j < 8; ++j) p += (float)v[j] * u[j];
        p += __shfl_xor(p, 1, 64);
        p += __shfl_xor(p, 2, 64);
        p += __shfl_xor(p, 4, 64);
        p += __shfl_xor(p, 8, 64);
        if (l16 == 0) slog[row] = p * gls[row];
    }
    __syncthreads();
}

__global__ __launch_bounds__(1024)
void tail_kernel(const __bf16* __restrict__ mall, const float* __restrict__ gp,
                 const float* __restrict__ query, const float* __restrict__ lbuf0,
                 float* __restrict__ out_logits, float* __restrict__ out_soft)
{
    __shared__ float gls[2048];       // gp[b,:]
    __shared__ float wls[2048];       // gp * softmax weights
    __shared__ float slog[2048];      // logits scratch
    __shared__ float part[16][128];
    __shared__ float ured[128];       // accumulated uq (uqA then +uqB)
    __shared__ float uvec[128];       // query + ured
    __shared__ float redm[16], reds[16];

    const int b    = blockIdx.x;
    const int tid  = threadIdx.x;
    const int wv   = tid >> 6;
    const int lane = tid & 63;

    const __bf16* m1 = mall + (size_t)b * MM * EE;
    const __bf16* m2 = mall + (size_t)32768 * EE + (size_t)b * MM * EE;

    gls[tid]        = gp[(size_t)b * MM + tid];
    gls[tid + 1024] = gp[(size_t)b * MM + tid + 1024];
    if (tid < 128) ured[tid] = 0.f;
    __syncthreads();

    // hop1
    softmax_weights(lbuf0 + (size_t)b * MM, gls, wls, redm, reds, tid, wv, lane);
    update_u(m1, wls, part, ured, tid, wv, lane);            // ured = uqA
    if (tid < 128) uvec[tid] = query[b * EE + tid] + ured[tid];
    __syncthreads();
    logits_u(m1, gls, uvec, slog, tid, wv, lane);            // slog = logits1

    // hop2
    softmax_weights(slog, gls, wls, redm, reds, tid, wv, lane);
    update_u(m2, wls, part, ured, tid, wv, lane);            // ured = uqA+uqB
    if (tid < 128) uvec[tid] = query[b * EE + tid] + ured[tid];
    __syncthreads();
    logits_u(m2, gls, uvec, slog, tid, wv, lane);            // slog = logits2

    // write logits + final softmax (from LDS)
    const float l0 = slog[tid], l1 = slog[tid + 1024];
    out_logits[(size_t)b * MM + tid]        = l0;
    out_logits[(size_t)b * MM + tid + 1024] = l1;

    float mx = fmaxf(l0, l1);
    #pragma unroll
    for (int off = 32; off > 0; off >>= 1) mx = fmaxf(mx, __shfl_xor(mx, off, 64));
    if (lane == 0) redm[wv] = mx;
    __syncthreads();
    mx = redm[0];
    #pragma unroll
    for (int k = 1; k < 16; ++k) mx = fmaxf(mx, redm[k]);
    const float e0 = __expf(l0 - mx), e1 = __expf(l1 - mx);
    float sum = e0 + e1;
    #pragma unroll
    for (int off = 32; off > 0; off >>= 1) sum += __shfl_xor(sum, off, 64);
    if (lane == 0) reds[wv] = sum;
    __syncthreads();
    float tot = reds[0];
    #pragma unroll
    for (int k = 1; k < 16; ++k) tot += reds[k];
    const float inv = 1.f / tot;
    out_soft[(size_t)b * MM + tid]        = e0 * inv;
    out_soft[(size_t)b * MM + tid + 1024] = e1 * inv;
}

// ---------------------------------------------------------------------------
extern "C" void kernel_launch(void* const* d_in, const int* in_sizes, int n_in,
                              void* d_out, int out_size, void* d_ws, size_t ws_size,
                              hipStream_t stream) {
    const int*   story    = (const int*)d_in[0];
    const int*   kb_len   = (const int*)d_in[1];
    const int*   conv_len = (const int*)d_in[2];
    // d_in[3] = hidden (dead w.r.t. outputs)
    const float* dh       = (const float*)d_in[4];
    const float* tf       = (const float*)d_in[5];
    const float* query    = (const float*)d_in[6];
    const float* gp       = (const float*)d_in[7];
    const float* C        = (const float*)d_in[8];
    const float* wA1      = (const float*)d_in[9];
    const float* bA1      = (const float*)d_in[10];
    const float* wA2      = (const float*)d_in[11];
    const float* bA2      = (const float*)d_in[12];
    // wC1/bC1/wC2/bC2, wf/bf: dead w.r.t. outputs

    char* ws = (char*)d_ws;
    const size_t M_ELEMS = (size_t)32768 * EE;
    size_t off = 0;
    __bf16* m   = (__bf16*)(ws + off); off += 2 * M_ELEMS * sizeof(__bf16);    // m1, m2
    __bf16* w1t = (__bf16*)(ws + off); off += 256 * 128 * sizeof(__bf16);
    __bf16* w2t = (__bf16*)(ws + off); off += 128 * 128 * sizeof(__bf16);
    float* lbuf = (float*)(ws + off);  off += (size_t)BB * MM * sizeof(float);

    float* out_soft   = (float*)d_out;
    float* out_logits = out_soft + (size_t)BB * MM;

    prep_small<<<N_PREP / 256, 256, 0, stream>>>(wA1, wA2, w1t, w2t);
    embed_mlp_mfma<<<3072, 256, 0, stream>>>(story, kb_len, conv_len, dh, tf, C,
                                             w1t, bA1, w2t, bA2, gp, query, m, lbuf);
    tail_kernel<<<BB, 1024, 0, stream>>>(m, gp, query, lbuf, out_logits, out_soft);
}

// Round 5
// 197.827 us; speedup vs baseline: 2.8151x; 1.0740x over previous
//
#include <hip/hip_runtime.h>
#include <math.h>

#define BB 16
#define MM 2048
#define SS 6
#define EE 128
#define LCC 512
#define VV 32000

typedef __attribute__((ext_vector_type(8))) __bf16 bf16x8;
typedef __attribute__((ext_vector_type(4))) float f32x4;

#define XS_STRIDE 264   // 256+8 bf16 pad
#define HS_STRIDE 136   // 128+8 bf16 pad

static __device__ inline unsigned short bfbits(float x) {
    __bf16 h = (__bf16)x;
    return __builtin_bit_cast(unsigned short, h);
}

// ---------------------------------------------------------------------------
// prep_small: W1/W2 fp32 -> bf16 transposed [n][k]; uqA = uqB = 0.
// ---------------------------------------------------------------------------
#define N_W1  (256 * 128)              // 32,768
#define N_W2  (128 * 128)              // 16,384
#define N_UQ  (BB * EE)                // 2,048
#define N_PREP (N_W1 + N_W2 + 2 * N_UQ)   // 53,248 = 208*256

__global__ __launch_bounds__(256)
void prep_small(const float* __restrict__ W1, const float* __restrict__ W2,
                __bf16* __restrict__ w1t, __bf16* __restrict__ w2t,
                float* __restrict__ uqA, float* __restrict__ uqB)
{
    int i = blockIdx.x * 256 + threadIdx.x;
    if (i < N_W1) { const int n = i >> 8, k = i & 255; w1t[i] = (__bf16)W1[k * EE + n]; return; }
    i -= N_W1;
    if (i < N_W2) { const int n = i >> 7, k = i & 127; w2t[i] = (__bf16)W2[k * EE + n]; return; }
    i -= N_W2;
    if (i < N_UQ) { uqA[i] = 0.f; return; }
    i -= N_UQ;
    if (i < N_UQ) { uqB[i] = 0.f; }
}

// ---------------------------------------------------------------------------
// Fused embed gather-sum (fp32 C, direct) + add_lm + MFMA MLP, 3 hops.
// hop 0: logits0 in-register, m0 never stored. hops 1,2: Y -> mout bf16.
// LDS: Hs/plog ALIAS Xs (Xs dead after GEMM1 K-loop; barrier-separated).
// Round-5 change: gather hoists ALL 24 C-loads + 4 dh-loads into registers
// before any consume (was 4 serial chunks of 6) — 4x memory-level parallelism
// on the latency-bound LLC gather (measured 2.2 TB/s, stall-bound).
// ---------------------------------------------------------------------------
__global__ __launch_bounds__(256)
void embed_mlp_mfma(const int* __restrict__ story,
                    const int* __restrict__ kb_len,
                    const int* __restrict__ conv_len,
                    const float* __restrict__ dh,
                    const float* __restrict__ tf,
                    const float* __restrict__ C,
                    const __bf16* __restrict__ w1t, const float* __restrict__ b1,
                    const __bf16* __restrict__ w2t, const float* __restrict__ b2,
                    const float* __restrict__ gp, const float* __restrict__ query,
                    __bf16* __restrict__ mout, float* __restrict__ lbuf0)
{
    __shared__ __bf16 Xs[32 * XS_STRIDE];   // 16,896 B; Hs (8,704 B) aliases
    __shared__ int    sidx[32 * SS];
    __bf16* Hs   = Xs;                      // valid: Xs dead before H written
    float*  plog = (float*)Xs;              // valid: Hs dead before plog written

    const int bid  = blockIdx.x;
    const int hop  = bid >> 10;
    const int row0 = (bid & 1023) * 32;
    const int b    = row0 >> 11;
    const int tid  = threadIdx.x;

    const float* Ck = C + (size_t)hop * VV * EE;

    for (int i = tid; i < 32 * SS; i += 256) sidx[i] = story[(size_t)row0 * SS + i];

    const int kb   = kb_len[b];
    const int cl   = conv_len[b];
    const int rgrp = tid >> 5;              // 0..7
    const int e4   = (tid & 31) * 4;        // 4-float col group
    const float4 tf4 = *(const float4*)&tf[b * EE + e4];
    ushort4 tfp;
    tfp.x = bfbits(tf4.x); tfp.y = bfbits(tf4.y); tfp.z = bfbits(tf4.z); tfp.w = bfbits(tf4.w);
    __syncthreads();

    // ---- gather X: ALL loads issued before any consume (max MLP) ----
    {
        float4 v[4][SS];
        #pragma unroll
        for (int chunk = 0; chunk < 4; ++chunk) {
            const int r = chunk * 8 + rgrp;
            #pragma unroll
            for (int s = 0; s < SS; ++s)
                v[chunk][s] = *(const float4*)&Ck[(size_t)sidx[r * SS + s] * EE + e4];
        }
        float4 dacc[4];
        #pragma unroll
        for (int chunk = 0; chunk < 4; ++chunk) {
            const int r = chunk * 8 + rgrp;
            const int j = ((row0 + r) & (MM - 1)) - kb;
            dacc[chunk] = (float4){0.f, 0.f, 0.f, 0.f};
            if (j >= 0 && j < cl)
                dacc[chunk] = *(const float4*)&dh[((size_t)b * LCC + j) * EE + e4];
        }
        #pragma unroll
        for (int chunk = 0; chunk < 4; ++chunk) {
            const int r = chunk * 8 + rgrp;
            float4 acc = dacc[chunk];
            #pragma unroll
            for (int s = 0; s < SS; ++s) {
                acc.x += v[chunk][s].x; acc.y += v[chunk][s].y;
                acc.z += v[chunk][s].z; acc.w += v[chunk][s].w;
            }
            ushort4 pk;
            pk.x = bfbits(acc.x); pk.y = bfbits(acc.y); pk.z = bfbits(acc.z); pk.w = bfbits(acc.w);
            *(ushort4*)&Xs[r * XS_STRIDE + e4]      = pk;
            *(ushort4*)&Xs[r * XS_STRIDE + EE + e4] = tfp;
        }
    }
    __syncthreads();

    const int w       = tid >> 6;
    const int lane    = tid & 63;
    const int lr      = lane & 15;
    const int lk      = lane >> 4;
    const int colbase = w * 32;

    // ---- GEMM1: H = lrelu(X @ W1 + b1) ----
    f32x4 acc1[2][2];
    #pragma unroll
    for (int i = 0; i < 2; ++i)
        #pragma unroll
        for (int j = 0; j < 2; ++j) acc1[i][j] = (f32x4){0.f, 0.f, 0.f, 0.f};

    for (int ks = 0; ks < 8; ++ks) {
        bf16x8 a[2], bw[2];
        #pragma unroll
        for (int mt = 0; mt < 2; ++mt)
            a[mt] = *(const bf16x8*)&Xs[(mt * 16 + lr) * XS_STRIDE + ks * 32 + lk * 8];
        #pragma unroll
        for (int nt = 0; nt < 2; ++nt)
            bw[nt] = *(const bf16x8*)&w1t[(size_t)(colbase + nt * 16 + lr) * 256 + ks * 32 + lk * 8];
        #pragma unroll
        for (int mt = 0; mt < 2; ++mt)
            #pragma unroll
            for (int nt = 0; nt < 2; ++nt)
                acc1[mt][nt] = __builtin_amdgcn_mfma_f32_16x16x32_bf16(a[mt], bw[nt], acc1[mt][nt], 0, 0, 0);
    }
    __syncthreads();   // all Xs reads complete before Hs (alias) is written
    {
        const float b1v[2] = { b1[colbase + lr], b1[colbase + 16 + lr] };
        #pragma unroll
        for (int mt = 0; mt < 2; ++mt)
            #pragma unroll
            for (int nt = 0; nt < 2; ++nt)
                #pragma unroll
                for (int reg = 0; reg < 4; ++reg) {
                    float h = acc1[mt][nt][reg] + b1v[nt];
                    h = (h > 0.f) ? h : 0.1f * h;
                    Hs[(mt * 16 + lk * 4 + reg) * HS_STRIDE + colbase + nt * 16 + lr] = (__bf16)h;
                }
    }
    __syncthreads();

    // ---- GEMM2: Y = H @ W2 + b2 ----
    f32x4 acc2[2][2];
    #pragma unroll
    for (int i = 0; i < 2; ++i)
        #pragma unroll
        for (int j = 0; j < 2; ++j) acc2[i][j] = (f32x4){0.f, 0.f, 0.f, 0.f};

    for (int ks = 0; ks < 4; ++ks) {
        bf16x8 a[2], bw[2];
        #pragma unroll
        for (int mt = 0; mt < 2; ++mt)
            a[mt] = *(const bf16x8*)&Hs[(mt * 16 + lr) * HS_STRIDE + ks * 32 + lk * 8];
        #pragma unroll
        for (int nt = 0; nt < 2; ++nt)
            bw[nt] = *(const bf16x8*)&w2t[(size_t)(colbase + nt * 16 + lr) * 128 + ks * 32 + lk * 8];
        #pragma unroll
        for (int mt = 0; mt < 2; ++mt)
            #pragma unroll
            for (int nt = 0; nt < 2; ++nt)
                acc2[mt][nt] = __builtin_amdgcn_mfma_f32_16x16x32_bf16(a[mt], bw[nt], acc2[mt][nt], 0, 0, 0);
    }

    const float b2v[2] = { b2[colbase + lr], b2[colbase + 16 + lr] };

    if (hop == 0) {
        const float qv0 = query[b * EE + colbase + lr];
        const float qv1 = query[b * EE + colbase + 16 + lr];
        __syncthreads();    // Hs reads done; reuse as plog
        #pragma unroll
        for (int mt = 0; mt < 2; ++mt)
            #pragma unroll
            for (int reg = 0; reg < 4; ++reg) {
                float p = (acc2[mt][0][reg] + b2v[0]) * qv0
                        + (acc2[mt][1][reg] + b2v[1]) * qv1;
                p += __shfl_xor(p, 1, 64);
                p += __shfl_xor(p, 2, 64);
                p += __shfl_xor(p, 4, 64);
                p += __shfl_xor(p, 8, 64);
                if (lr == 0) plog[(mt * 16 + lk * 4 + reg) * 4 + w] = p;
            }
        __syncthreads();
        if (tid < 32) {
            const float l = plog[tid * 4] + plog[tid * 4 + 1] + plog[tid * 4 + 2] + plog[tid * 4 + 3];
            lbuf0[row0 + tid] = l * gp[row0 + tid];
        }
    } else {
        __bf16* out = mout + (size_t)(hop - 1) * 32768 * EE;
        #pragma unroll
        for (int mt = 0; mt < 2; ++mt)
            #pragma unroll
            for (int nt = 0; nt < 2; ++nt)
                #pragma unroll
                for (int reg = 0; reg < 4; ++reg) {
                    const int rg_ = row0 + mt * 16 + lk * 4 + reg;
                    out[(size_t)rg_ * EE + colbase + nt * 16 + lr] =
                        (__bf16)(acc2[mt][nt][reg] + b2v[nt]);
                }
    }
}

// ---------------------------------------------------------------------------
// update: inline softmax of lbuf[b,:], then uq[b,:] += sum_{64 rows} gp*soft*mk.
// 512 blocks x 256.
// ---------------------------------------------------------------------------
__global__ __launch_bounds__(256)
void update_kernel(const __bf16* __restrict__ mk, const float* __restrict__ gp,
                   const float* __restrict__ lbuf, float* __restrict__ uq)
{
    __shared__ float redm[4], reds[4];
    __shared__ float wls[64];
    __shared__ float part[4][128];

    const int b      = blockIdx.x >> 5;
    const int rloc0  = (blockIdx.x & 31) * 64;
    const int tid    = threadIdx.x;
    const int lane   = tid & 63;
    const int w      = tid >> 6;
    const float* lb  = lbuf + (size_t)b * MM;

    float v[8];
    float mx = -1e30f;
    #pragma unroll
    for (int i = 0; i < 8; ++i) { v[i] = lb[i * 256 + tid]; mx = fmaxf(mx, v[i]); }
    #pragma unroll
    for (int off = 32; off > 0; off >>= 1) mx = fmaxf(mx, __shfl_xor(mx, off, 64));
    if (lane == 0) redm[w] = mx;
    __syncthreads();
    mx = fmaxf(fmaxf(redm[0], redm[1]), fmaxf(redm[2], redm[3]));
    float sum = 0.f;
    #pragma unroll
    for (int i = 0; i < 8; ++i) sum += __expf(v[i] - mx);
    #pragma unroll
    for (int off = 32; off > 0; off >>= 1) sum += __shfl_xor(sum, off, 64);
    if (lane == 0) reds[w] = sum;
    __syncthreads();
    const float inv = 1.f / (reds[0] + reds[1] + reds[2] + reds[3]);

    if (tid < 64)
        wls[tid] = gp[(size_t)b * MM + rloc0 + tid] * __expf(lb[rloc0 + tid] - mx) * inv;
    __syncthreads();

    const int rgrp = tid >> 4;
    const int e8   = (tid & 15) * 8;
    float acc[8];
    #pragma unroll
    for (int q = 0; q < 8; ++q) acc[q] = 0.f;
    #pragma unroll
    for (int p = 0; p < 4; ++p) {
        const int rl  = p * 16 + rgrp;
        const float wg = wls[rl];
        const bf16x8 vv = *(const bf16x8*)&mk[((size_t)b * MM + rloc0 + rl) * EE + e8];
        #pragma unroll
        for (int q = 0; q < 8; ++q) acc[q] += wg * (float)vv[q];
    }
    #pragma unroll
    for (int q = 0; q < 8; ++q) {
        acc[q] += __shfl_xor(acc[q], 16, 64);
        acc[q] += __shfl_xor(acc[q], 32, 64);
    }
    if (lane < 16) {
        #pragma unroll
        for (int q = 0; q < 8; ++q) part[w][e8 + q] = acc[q];
    }
    __syncthreads();
    if (tid < 128) {
        const float s = part[0][tid] + part[1][tid] + part[2][tid] + part[3][tid];
        atomicAdd(&uq[b * EE + tid], s);
    }
}

// ---------------------------------------------------------------------------
// logits[row] = gp[row] * dot(mk[row,:], query[b]+uqa[b](+uqb[b])).
// 512 blocks x 64 rows.
// ---------------------------------------------------------------------------
__global__ __launch_bounds__(256)
void logits_kernel(const __bf16* __restrict__ mk, const float* __restrict__ gp,
                   const float* __restrict__ query, const float* __restrict__ uqa,
                   const float* __restrict__ uqb, float* __restrict__ out)
{
    __shared__ float uqs[128];
    const int row0 = blockIdx.x * 64;
    const int b    = row0 >> 11;
    const int tid  = threadIdx.x;
    if (tid < 128)
        uqs[tid] = query[b * EE + tid] + uqa[b * EE + tid]
                 + (uqb ? uqb[b * EE + tid] : 0.f);
    __syncthreads();
    const int w = tid >> 6, lane = tid & 63;
    const int g = lane >> 4, l16 = lane & 15;
    float u[8];
    #pragma unroll
    for (int j = 0; j < 8; ++j) u[j] = uqs[l16 * 8 + j];
    #pragma unroll
    for (int it = 0; it < 4; ++it) {
        const int row = row0 + it * 16 + w * 4 + g;
        const bf16x8 v = *(const bf16x8*)&mk[(size_t)row * EE + l16 * 8];
        float p = 0.f;
        #pragma unroll
        for (int j = 0; j < 8; ++j) p += (float)v[j] * u[j];
        p += __shfl_xor(p, 1, 64);
        p += __shfl_xor(p, 2, 64);
        p += __shfl_xor(p, 4, 64);
        p += __shfl_xor(p, 8, 64);
        if (l16 == 0) out[row] = p * gp[row];
    }
}

// ---------------------------------------------------------------------------
// final softmax: block per b.
// ---------------------------------------------------------------------------
__global__ __launch_bounds__(256)
void softmax_final(const float* __restrict__ logits, float* __restrict__ soft)
{
    __shared__ float redm[4], reds[4];
    const int b = blockIdx.x, tid = threadIdx.x;
    const int lane = tid & 63, w = tid >> 6;
    const float* lb = logits + (size_t)b * MM;
    float v[8];
    float mx = -1e30f;
    #pragma unroll
    for (int i = 0; i < 8; ++i) { v[i] = lb[i * 256 + tid]; mx = fmaxf(mx, v[i]); }
    #pragma unroll
    for (int off = 32; off > 0; off >>= 1) mx = fmaxf(mx, __shfl_xor(mx, off, 64));
    if (lane == 0) redm[w] = mx;
    __syncthreads();
    mx = fmaxf(fmaxf(redm[0], redm[1]), fmaxf(redm[2], redm[3]));
    float sum = 0.f;
    #pragma unroll
    for (int i = 0; i < 8; ++i) { v[i] = __expf(v[i] - mx); sum += v[i]; }
    #pragma unroll
    for (int off = 32; off > 0; off >>= 1) sum += __shfl_xor(sum, off, 64);
    if (lane == 0) reds[w] = sum;
    __syncthreads();
    const float inv = 1.f / (reds[0] + reds[1] + reds[2] + reds[3]);
    #pragma unroll
    for (int i = 0; i < 8; ++i) soft[(size_t)b * MM + i * 256 + tid] = v[i] * inv;
}

// ---------------------------------------------------------------------------
extern "C" void kernel_launch(void* const* d_in, const int* in_sizes, int n_in,
                              void* d_out, int out_size, void* d_ws, size_t ws_size,
                              hipStream_t stream) {
    const int*   story    = (const int*)d_in[0];
    const int*   kb_len   = (const int*)d_in[1];
    const int*   conv_len = (const int*)d_in[2];
    // d_in[3] = hidden (dead w.r.t. outputs)
    const float* dh       = (const float*)d_in[4];
    const float* tf       = (const float*)d_in[5];
    const float* query    = (const float*)d_in[6];
    const float* gp       = (const float*)d_in[7];
    const float* C        = (const float*)d_in[8];
    const float* wA1      = (const float*)d_in[9];
    const float* bA1      = (const float*)d_in[10];
    const float* wA2      = (const float*)d_in[11];
    const float* bA2      = (const float*)d_in[12];
    // wC1/bC1/wC2/bC2, wf/bf: dead w.r.t. outputs

    char* ws = (char*)d_ws;
    const size_t M_ELEMS = (size_t)32768 * EE;
    size_t off = 0;
    __bf16* m   = (__bf16*)(ws + off); off += 2 * M_ELEMS * sizeof(__bf16);    // m1, m2
    __bf16* w1t = (__bf16*)(ws + off); off += 256 * 128 * sizeof(__bf16);
    __bf16* w2t = (__bf16*)(ws + off); off += 128 * 128 * sizeof(__bf16);
    float* lbuf = (float*)(ws + off);  off += (size_t)BB * MM * sizeof(float);
    float* uqA  = (float*)(ws + off);  off += (size_t)BB * EE * sizeof(float);
    float* uqB  = (float*)(ws + off);  off += (size_t)BB * EE * sizeof(float);

    float* out_soft   = (float*)d_out;
    float* out_logits = out_soft + (size_t)BB * MM;

    prep_small<<<N_PREP / 256, 256, 0, stream>>>(wA1, wA2, w1t, w2t, uqA, uqB);
    embed_mlp_mfma<<<3072, 256, 0, stream>>>(story, kb_len, conv_len, dh, tf, C,
                                             w1t, bA1, w2t, bA2, gp, query, m, lbuf);
    // hop1: uqA = m1^T(gp*soft0);  logits1 = gp*(m1 (query+uqA)) -> lbuf
    update_kernel<<<512, 256, 0, stream>>>(m, gp, lbuf, uqA);
    logits_kernel<<<512, 256, 0, stream>>>(m, gp, query, uqA, nullptr, lbuf);
    // hop2: uqB = m2^T(gp*soft1);  logits2 = gp*(m2 (query+uqA+uqB)) -> out
    update_kernel<<<512, 256, 0, stream>>>(m + M_ELEMS, gp, lbuf, uqB);
    logits_kernel<<<512, 256, 0, stream>>>(m + M_ELEMS, gp, query, uqA, uqB, out_logits);
    softmax_final<<<BB, 256, 0, stream>>>(out_logits, out_soft);
}

// Round 6
// 195.144 us; speedup vs baseline: 2.8539x; 1.0138x over previous
//
#include <hip/hip_runtime.h>
#include <math.h>

#define BB 16
#define MM 2048
#define SS 6
#define EE 128
#define LCC 512
#define VV 32000

typedef __attribute__((ext_vector_type(8))) __bf16 bf16x8;
typedef __attribute__((ext_vector_type(4))) __bf16 bf16x4;
typedef __attribute__((ext_vector_type(4))) float f32x4;

#define XS_STRIDE 264   // 256+8 bf16 pad
#define HS_STRIDE 136   // 128+8 bf16 pad

static __device__ inline unsigned short bfbits(float x) {
    __bf16 h = (__bf16)x;
    return __builtin_bit_cast(unsigned short, h);
}

// ---------------------------------------------------------------------------
// prep: W1/W2 fp32 -> bf16 transposed [n][k]; uqA = uqB = 0;
// C[0..2] fp32 -> bf16 (halves the gather bytes in embed_mlp_mfma).
// Blocks [0,208): weights+uq.  Blocks [208, 208+6000): C conversion,
// 8 elems/thread (3*32000*128 = 12,288,000 = 6000*256*8 exactly).
// ---------------------------------------------------------------------------
#define N_W1  (256 * 128)              // 32,768
#define N_W2  (128 * 128)              // 16,384
#define N_UQ  (BB * EE)                // 2,048
#define N_SMALL (N_W1 + N_W2 + 2 * N_UQ)   // 53,248 = 208*256
#define SMALL_BLOCKS 208
#define N_C   (3 * VV * EE)            // 12,288,000
#define C_BLOCKS 6000                  // N_C / (256*8)
#define PREP_BLOCKS (SMALL_BLOCKS + C_BLOCKS)

__global__ __launch_bounds__(256)
void prep_kernel(const float* __restrict__ W1, const float* __restrict__ W2,
                 const float* __restrict__ C,
                 __bf16* __restrict__ w1t, __bf16* __restrict__ w2t,
                 __bf16* __restrict__ Cb,
                 float* __restrict__ uqA, float* __restrict__ uqB)
{
    if (blockIdx.x < SMALL_BLOCKS) {
        int i = blockIdx.x * 256 + threadIdx.x;
        if (i < N_W1) { const int n = i >> 8, k = i & 255; w1t[i] = (__bf16)W1[k * EE + n]; return; }
        i -= N_W1;
        if (i < N_W2) { const int n = i >> 7, k = i & 127; w2t[i] = (__bf16)W2[k * EE + n]; return; }
        i -= N_W2;
        if (i < N_UQ) { uqA[i] = 0.f; return; }
        i -= N_UQ;
        if (i < N_UQ) { uqB[i] = 0.f; }
        return;
    }
    const size_t base = ((size_t)(blockIdx.x - SMALL_BLOCKS) * 256 + threadIdx.x) * 8;
    const float4 a = *(const float4*)&C[base];
    const float4 b = *(const float4*)&C[base + 4];
    bf16x8 h;
    h[0] = (__bf16)a.x; h[1] = (__bf16)a.y; h[2] = (__bf16)a.z; h[3] = (__bf16)a.w;
    h[4] = (__bf16)b.x; h[5] = (__bf16)b.y; h[6] = (__bf16)b.z; h[7] = (__bf16)b.w;
    *(bf16x8*)&Cb[base] = h;
}

// ---------------------------------------------------------------------------
// Fused embed gather-sum (bf16 C tables) + add_lm + MFMA MLP, 3 hops.
// hop 0: logits0 in-register, m0 never stored. hops 1,2: Y -> mout bf16.
// LDS: Hs/plog ALIAS Xs (Xs dead after GEMM1 K-loop; barrier-separated).
// Gather: round-0 chunked form (VGPR 44, occ ~44%) — round-5 full hoist
// regressed (VGPR 76 -> occ 28%, TLP loss > ILP gain).  bf16 tables halve
// gather bytes and double per-XCD L2 hit rate (8 MB table vs 4 MB L2).
// ---------------------------------------------------------------------------
__global__ __launch_bounds__(256)
void embed_mlp_mfma(const int* __restrict__ story,
                    const int* __restrict__ kb_len,
                    const int* __restrict__ conv_len,
                    const float* __restrict__ dh,
                    const float* __restrict__ tf,
                    const __bf16* __restrict__ Cb,
                    const __bf16* __restrict__ w1t, const float* __restrict__ b1,
                    const __bf16* __restrict__ w2t, const float* __restrict__ b2,
                    const float* __restrict__ gp, const float* __restrict__ query,
                    __bf16* __restrict__ mout, float* __restrict__ lbuf0)
{
    __shared__ __bf16 Xs[32 * XS_STRIDE];   // 16,896 B; Hs (8,704 B) aliases
    __shared__ int    sidx[32 * SS];
    __bf16* Hs   = Xs;                      // valid: Xs dead before H written
    float*  plog = (float*)Xs;              // valid: Hs dead before plog written

    const int bid  = blockIdx.x;
    const int hop  = bid >> 10;
    const int row0 = (bid & 1023) * 32;
    const int b    = row0 >> 11;
    const int tid  = threadIdx.x;

    const __bf16* Ck = Cb + (size_t)hop * VV * EE;

    for (int i = tid; i < 32 * SS; i += 256) sidx[i] = story[(size_t)row0 * SS + i];

    const int kb   = kb_len[b];
    const int cl   = conv_len[b];
    const int rgrp = tid >> 5;              // 0..7
    const int e4   = (tid & 31) * 4;        // 4-elem col group
    const float4 tf4 = *(const float4*)&tf[b * EE + e4];
    ushort4 tfp;
    tfp.x = bfbits(tf4.x); tfp.y = bfbits(tf4.y); tfp.z = bfbits(tf4.z); tfp.w = bfbits(tf4.w);
    __syncthreads();

    // ---- gather X: bf16x4 row reads, fp32 accumulate, packed bf16x4 stores ----
    for (int chunk = 0; chunk < 4; ++chunk) {
        const int r  = chunk * 8 + rgrp;
        const int* si = &sidx[r * SS];
        bf16x4 v[SS];
        #pragma unroll
        for (int s = 0; s < SS; ++s)
            v[s] = *(const bf16x4*)&Ck[(size_t)si[s] * EE + e4];
        const int j = ((row0 + r) & (MM - 1)) - kb;
        float4 acc = {0.f, 0.f, 0.f, 0.f};
        if (j >= 0 && j < cl)
            acc = *(const float4*)&dh[((size_t)b * LCC + j) * EE + e4];
        #pragma unroll
        for (int s = 0; s < SS; ++s) {
            acc.x += (float)v[s][0]; acc.y += (float)v[s][1];
            acc.z += (float)v[s][2]; acc.w += (float)v[s][3];
        }
        ushort4 pk;
        pk.x = bfbits(acc.x); pk.y = bfbits(acc.y); pk.z = bfbits(acc.z); pk.w = bfbits(acc.w);
        *(ushort4*)&Xs[r * XS_STRIDE + e4]      = pk;
        *(ushort4*)&Xs[r * XS_STRIDE + EE + e4] = tfp;
    }
    __syncthreads();

    const int w       = tid >> 6;
    const int lane    = tid & 63;
    const int lr      = lane & 15;
    const int lk      = lane >> 4;
    const int colbase = w * 32;

    // ---- GEMM1: H = lrelu(X @ W1 + b1) ----
    f32x4 acc1[2][2];
    #pragma unroll
    for (int i = 0; i < 2; ++i)
        #pragma unroll
        for (int j = 0; j < 2; ++j) acc1[i][j] = (f32x4){0.f, 0.f, 0.f, 0.f};

    for (int ks = 0; ks < 8; ++ks) {
        bf16x8 a[2], bw[2];
        #pragma unroll
        for (int mt = 0; mt < 2; ++mt)
            a[mt] = *(const bf16x8*)&Xs[(mt * 16 + lr) * XS_STRIDE + ks * 32 + lk * 8];
        #pragma unroll
        for (int nt = 0; nt < 2; ++nt)
            bw[nt] = *(const bf16x8*)&w1t[(size_t)(colbase + nt * 16 + lr) * 256 + ks * 32 + lk * 8];
        #pragma unroll
        for (int mt = 0; mt < 2; ++mt)
            #pragma unroll
            for (int nt = 0; nt < 2; ++nt)
                acc1[mt][nt] = __builtin_amdgcn_mfma_f32_16x16x32_bf16(a[mt], bw[nt], acc1[mt][nt], 0, 0, 0);
    }
    __syncthreads();   // all Xs reads complete before Hs (alias) is written
    {
        const float b1v[2] = { b1[colbase + lr], b1[colbase + 16 + lr] };
        #pragma unroll
        for (int mt = 0; mt < 2; ++mt)
            #pragma unroll
            for (int nt = 0; nt < 2; ++nt)
                #pragma unroll
                for (int reg = 0; reg < 4; ++reg) {
                    float h = acc1[mt][nt][reg] + b1v[nt];
                    h = (h > 0.f) ? h : 0.1f * h;
                    Hs[(mt * 16 + lk * 4 + reg) * HS_STRIDE + colbase + nt * 16 + lr] = (__bf16)h;
                }
    }
    __syncthreads();

    // ---- GEMM2: Y = H @ W2 + b2 ----
    f32x4 acc2[2][2];
    #pragma unroll
    for (int i = 0; i < 2; ++i)
        #pragma unroll
        for (int j = 0; j < 2; ++j) acc2[i][j] = (f32x4){0.f, 0.f, 0.f, 0.f};

    for (int ks = 0; ks < 4; ++ks) {
        bf16x8 a[2], bw[2];
        #pragma unroll
        for (int mt = 0; mt < 2; ++mt)
            a[mt] = *(const bf16x8*)&Hs[(mt * 16 + lr) * HS_STRIDE + ks * 32 + lk * 8];
        #pragma unroll
        for (int nt = 0; nt < 2; ++nt)
            bw[nt] = *(const bf16x8*)&w2t[(size_t)(colbase + nt * 16 + lr) * 128 + ks * 32 + lk * 8];
        #pragma unroll
        for (int mt = 0; mt < 2; ++mt)
            #pragma unroll
            for (int nt = 0; nt < 2; ++nt)
                acc2[mt][nt] = __builtin_amdgcn_mfma_f32_16x16x32_bf16(a[mt], bw[nt], acc2[mt][nt], 0, 0, 0);
    }

    const float b2v[2] = { b2[colbase + lr], b2[colbase + 16 + lr] };

    if (hop == 0) {
        const float qv0 = query[b * EE + colbase + lr];
        const float qv1 = query[b * EE + colbase + 16 + lr];
        __syncthreads();    // Hs reads done; reuse as plog
        #pragma unroll
        for (int mt = 0; mt < 2; ++mt)
            #pragma unroll
            for (int reg = 0; reg < 4; ++reg) {
                float p = (acc2[mt][0][reg] + b2v[0]) * qv0
                        + (acc2[mt][1][reg] + b2v[1]) * qv1;
                p += __shfl_xor(p, 1, 64);
                p += __shfl_xor(p, 2, 64);
                p += __shfl_xor(p, 4, 64);
                p += __shfl_xor(p, 8, 64);
                if (lr == 0) plog[(mt * 16 + lk * 4 + reg) * 4 + w] = p;
            }
        __syncthreads();
        if (tid < 32) {
            const float l = plog[tid * 4] + plog[tid * 4 + 1] + plog[tid * 4 + 2] + plog[tid * 4 + 3];
            lbuf0[row0 + tid] = l * gp[row0 + tid];
        }
    } else {
        __bf16* out = mout + (size_t)(hop - 1) * 32768 * EE;
        #pragma unroll
        for (int mt = 0; mt < 2; ++mt)
            #pragma unroll
            for (int nt = 0; nt < 2; ++nt)
                #pragma unroll
                for (int reg = 0; reg < 4; ++reg) {
                    const int rg_ = row0 + mt * 16 + lk * 4 + reg;
                    out[(size_t)rg_ * EE + colbase + nt * 16 + lr] =
                        (__bf16)(acc2[mt][nt][reg] + b2v[nt]);
                }
    }
}

// ---------------------------------------------------------------------------
// update: inline softmax of lbuf[b,:], then uq[b,:] += sum_{64 rows} gp*soft*mk.
// 512 blocks x 256.
// ---------------------------------------------------------------------------
__global__ __launch_bounds__(256)
void update_kernel(const __bf16* __restrict__ mk, const float* __restrict__ gp,
                   const float* __restrict__ lbuf, float* __restrict__ uq)
{
    __shared__ float redm[4], reds[4];
    __shared__ float wls[64];
    __shared__ float part[4][128];

    const int b      = blockIdx.x >> 5;
    const int rloc0  = (blockIdx.x & 31) * 64;
    const int tid    = threadIdx.x;
    const int lane   = tid & 63;
    const int w      = tid >> 6;
    const float* lb  = lbuf + (size_t)b * MM;

    float v[8];
    float mx = -1e30f;
    #pragma unroll
    for (int i = 0; i < 8; ++i) { v[i] = lb[i * 256 + tid]; mx = fmaxf(mx, v[i]); }
    #pragma unroll
    for (int off = 32; off > 0; off >>= 1) mx = fmaxf(mx, __shfl_xor(mx, off, 64));
    if (lane == 0) redm[w] = mx;
    __syncthreads();
    mx = fmaxf(fmaxf(redm[0], redm[1]), fmaxf(redm[2], redm[3]));
    float sum = 0.f;
    #pragma unroll
    for (int i = 0; i < 8; ++i) sum += __expf(v[i] - mx);
    #pragma unroll
    for (int off = 32; off > 0; off >>= 1) sum += __shfl_xor(sum, off, 64);
    if (lane == 0) reds[w] = sum;
    __syncthreads();
    const float inv = 1.f / (reds[0] + reds[1] + reds[2] + reds[3]);

    if (tid < 64)
        wls[tid] = gp[(size_t)b * MM + rloc0 + tid] * __expf(lb[rloc0 + tid] - mx) * inv;
    __syncthreads();

    const int rgrp = tid >> 4;
    const int e8   = (tid & 15) * 8;
    float acc[8];
    #pragma unroll
    for (int q = 0; q < 8; ++q) acc[q] = 0.f;
    #pragma unroll
    for (int p = 0; p < 4; ++p) {
        const int rl  = p * 16 + rgrp;
        const float wg = wls[rl];
        const bf16x8 vv = *(const bf16x8*)&mk[((size_t)b * MM + rloc0 + rl) * EE + e8];
        #pragma unroll
        for (int q = 0; q < 8; ++q) acc[q] += wg * (float)vv[q];
    }
    #pragma unroll
    for (int q = 0; q < 8; ++q) {
        acc[q] += __shfl_xor(acc[q], 16, 64);
        acc[q] += __shfl_xor(acc[q], 32, 64);
    }
    if (lane < 16) {
        #pragma unroll
        for (int q = 0; q < 8; ++q) part[w][e8 + q] = acc[q];
    }
    __syncthreads();
    if (tid < 128) {
        const float s = part[0][tid] + part[1][tid] + part[2][tid] + part[3][tid];
        atomicAdd(&uq[b * EE + tid], s);
    }
}

// ---------------------------------------------------------------------------
// logits[row] = gp[row] * dot(mk[row,:], query[b]+uqa[b](+uqb[b])).
// 512 blocks x 64 rows.
// ---------------------------------------------------------------------------
__global__ __launch_bounds__(256)
void logits_kernel(const __bf16* __restrict__ mk, const float* __restrict__ gp,
                   const float* __restrict__ query, const float* __restrict__ uqa,
                   const float* __restrict__ uqb, float* __restrict__ out)
{
    __shared__ float uqs[128];
    const int row0 = blockIdx.x * 64;
    const int b    = row0 >> 11;
    const int tid  = threadIdx.x;
    if (tid < 128)
        uqs[tid] = query[b * EE + tid] + uqa[b * EE + tid]
                 + (uqb ? uqb[b * EE + tid] : 0.f);
    __syncthreads();
    const int w = tid >> 6, lane = tid & 63;
    const int g = lane >> 4, l16 = lane & 15;
    float u[8];
    #pragma unroll
    for (int j = 0; j < 8; ++j) u[j] = uqs[l16 * 8 + j];
    #pragma unroll
    for (int it = 0; it < 4; ++it) {
        const int row = row0 + it * 16 + w * 4 + g;
        const bf16x8 v = *(const bf16x8*)&mk[(size_t)row * EE + l16 * 8];
        float p = 0.f;
        #pragma unroll
        for (int j = 0; j < 8; ++j) p += (float)v[j] * u[j];
        p += __shfl_xor(p, 1, 64);
        p += __shfl_xor(p, 2, 64);
        p += __shfl_xor(p, 4, 64);
        p += __shfl_xor(p, 8, 64);
        if (l16 == 0) out[row] = p * gp[row];
    }
}

// ---------------------------------------------------------------------------
// final softmax: block per b.
// ---------------------------------------------------------------------------
__global__ __launch_bounds__(256)
void softmax_final(const float* __restrict__ logits, float* __restrict__ soft)
{
    __shared__ float redm[4], reds[4];
    const int b = blockIdx.x, tid = threadIdx.x;
    const int lane = tid & 63, w = tid >> 6;
    const float* lb = logits + (size_t)b * MM;
    float v[8];
    float mx = -1e30f;
    #pragma unroll
    for (int i = 0; i < 8; ++i) { v[i] = lb[i * 256 + tid]; mx = fmaxf(mx, v[i]); }
    #pragma unroll
    for (int off = 32; off > 0; off >>= 1) mx = fmaxf(mx, __shfl_xor(mx, off, 64));
    if (lane == 0) redm[w] = mx;
    __syncthreads();
    mx = fmaxf(fmaxf(redm[0], redm[1]), fmaxf(redm[2], redm[3]));
    float sum = 0.f;
    #pragma unroll
    for (int i = 0; i < 8; ++i) { v[i] = __expf(v[i] - mx); sum += v[i]; }
    #pragma unroll
    for (int off = 32; off > 0; off >>= 1) sum += __shfl_xor(sum, off, 64);
    if (lane == 0) reds[w] = sum;
    __syncthreads();
    const float inv = 1.f / (reds[0] + reds[1] + reds[2] + reds[3]);
    #pragma unroll
    for (int i = 0; i < 8; ++i) soft[(size_t)b * MM + i * 256 + tid] = v[i] * inv;
}

// ---------------------------------------------------------------------------
extern "C" void kernel_launch(void* const* d_in, const int* in_sizes, int n_in,
                              void* d_out, int out_size, void* d_ws, size_t ws_size,
                              hipStream_t stream) {
    const int*   story    = (const int*)d_in[0];
    const int*   kb_len   = (const int*)d_in[1];
    const int*   conv_len = (const int*)d_in[2];
    // d_in[3] = hidden (dead w.r.t. outputs)
    const float* dh       = (const float*)d_in[4];
    const float* tf       = (const float*)d_in[5];
    const float* query    = (const float*)d_in[6];
    const float* gp       = (const float*)d_in[7];
    const float* C        = (const float*)d_in[8];
    const float* wA1      = (const float*)d_in[9];
    const float* bA1      = (const float*)d_in[10];
    const float* wA2      = (const float*)d_in[11];
    const float* bA2      = (const float*)d_in[12];
    // wC1/bC1/wC2/bC2, wf/bf: dead w.r.t. outputs

    char* ws = (char*)d_ws;
    const size_t M_ELEMS = (size_t)32768 * EE;
    size_t off = 0;
    __bf16* m   = (__bf16*)(ws + off); off += 2 * M_ELEMS * sizeof(__bf16);    // m1, m2
    __bf16* Cb  = (__bf16*)(ws + off); off += (size_t)N_C * sizeof(__bf16);    // bf16 C[0..2]
    __bf16* w1t = (__bf16*)(ws + off); off += 256 * 128 * sizeof(__bf16);
    __bf16* w2t = (__bf16*)(ws + off); off += 128 * 128 * sizeof(__bf16);
    float* lbuf = (float*)(ws + off);  off += (size_t)BB * MM * sizeof(float);
    float* uqA  = (float*)(ws + off);  off += (size_t)BB * EE * sizeof(float);
    float* uqB  = (float*)(ws + off);  off += (size_t)BB * EE * sizeof(float);

    float* out_soft   = (float*)d_out;
    float* out_logits = out_soft + (size_t)BB * MM;

    prep_kernel<<<PREP_BLOCKS, 256, 0, stream>>>(wA1, wA2, C, w1t, w2t, Cb, uqA, uqB);
    embed_mlp_mfma<<<3072, 256, 0, stream>>>(story, kb_len, conv_len, dh, tf, Cb,
                                             w1t, bA1, w2t, bA2, gp, query, m, lbuf);
    // hop1: uqA = m1^T(gp*soft0);  logits1 = gp*(m1 (query+uqA)) -> lbuf
    update_kernel<<<512, 256, 0, stream>>>(m, gp, lbuf, uqA);
    logits_kernel<<<512, 256, 0, stream>>>(m, gp, query, uqA, nullptr, lbuf);
    // hop2: uqB = m2^T(gp*soft1);  logits2 = gp*(m2 (query+uqA+uqB)) -> out
    update_kernel<<<512, 256, 0, stream>>>(m + M_ELEMS, gp, lbuf, uqB);
    logits_kernel<<<512, 256, 0, stream>>>(m + M_ELEMS, gp, query, uqA, uqB, out_logits);
    softmax_final<<<BB, 256, 0, stream>>>(out_logits, out_soft);
}